// Round 9
// baseline (343.614 us; speedup 1.0000x reference)
//
#include <hip/hip_runtime.h>

#define D 128
#define CPAD 32   // one counter per 128B line (atomic line-contention hypothesis)

typedef __attribute__((ext_vector_type(8)))  short s16x8;
typedef __attribute__((ext_vector_type(4)))  short s16x4;
typedef __attribute__((ext_vector_type(16))) float f32x16;

static __device__ __forceinline__ unsigned short f2bf(float x) {
    unsigned u = __builtin_bit_cast(unsigned, x);
    unsigned r = (u + 0x7FFF + ((u >> 16) & 1)) >> 16;   // RNE
    return (unsigned short)r;
}
static __device__ __forceinline__ float bf2f(unsigned short h) {
    unsigned u = ((unsigned)h) << 16;
    return __builtin_bit_cast(float, u);
}

// ---------------- CSR build ----------------

__global__ void zero_pad_kernel(int* __restrict__ a, int* __restrict__ b, int n4) {
    int i = blockIdx.x * blockDim.x + threadIdx.x;
    if (i < n4) {
        *(int4*)(a + i * 4) = make_int4(0, 0, 0, 0);
        *(int4*)(b + i * 4) = make_int4(0, 0, 0, 0);
    }
}

// counters padded to CPAD ints apart (line-contention test; round-7 showed ILP doesn't help)
__global__ void count_rank_kernel(const int* __restrict__ hf_dst, const int* __restrict__ tt_dst,
                                  int* __restrict__ deg_hf, int* __restrict__ deg_tt,
                                  unsigned short* __restrict__ rank_hf,
                                  unsigned short* __restrict__ rank_tt,
                                  int E1, int E2) {
    int i = blockIdx.x * blockDim.x + threadIdx.x;
    if (i < E1) {
        int r = atomicAdd(&deg_hf[hf_dst[i] * CPAD], 1);
        rank_hf[i] = (unsigned short)r;
    }
    if (i < E2) {
        int r = atomicAdd(&deg_tt[tt_dst[i] * CPAD], 1);
        rank_tt[i] = (unsigned short)r;
    }
}

#define SCAN_EPB 1024

__global__ __launch_bounds__(256) void scan_blocks_kernel(
    const int* __restrict__ deg_hf, int* __restrict__ rp_hf, int* __restrict__ bs_hf,
    const int* __restrict__ deg_tt, int* __restrict__ rp_tt, int* __restrict__ bs_tt,
    int n, int nb)
{
    int gid = blockIdx.x;
    const int* deg; int* rp; int* bs; int b;
    if (gid < nb) { deg = deg_hf; rp = rp_hf; bs = bs_hf; b = gid; }
    else         { deg = deg_tt; rp = rp_tt; bs = bs_tt; b = gid - nb; }
    int t = threadIdx.x;
    int i0 = b * SCAN_EPB + t * 4;
    int4 v = make_int4(0, 0, 0, 0);
    if (i0 + 0 < n) v.x = deg[(size_t)(i0 + 0) * CPAD];
    if (i0 + 1 < n) v.y = deg[(size_t)(i0 + 1) * CPAD];
    if (i0 + 2 < n) v.z = deg[(size_t)(i0 + 2) * CPAD];
    if (i0 + 3 < n) v.w = deg[(size_t)(i0 + 3) * CPAD];
    __shared__ int sm[256];
    sm[t] = v.x + v.y + v.z + v.w;
    __syncthreads();
    for (int off = 1; off < 256; off <<= 1) {
        int x = (t >= off) ? sm[t - off] : 0;
        __syncthreads();
        sm[t] += x;
        __syncthreads();
    }
    int excl = (t > 0) ? sm[t - 1] : 0;
    if (i0 + 0 < n) rp[i0 + 0] = excl;
    if (i0 + 1 < n) rp[i0 + 1] = excl + v.x;
    if (i0 + 2 < n) rp[i0 + 2] = excl + v.x + v.y;
    if (i0 + 3 < n) rp[i0 + 3] = excl + v.x + v.y + v.z;
    if (t == 255) bs[b] = sm[255];
}

__global__ __launch_bounds__(256) void scan_offsets_kernel(
    int* __restrict__ rp_hf, const int* __restrict__ bs_hf,
    int* __restrict__ rp_tt, const int* __restrict__ bs_tt,
    int n, int nb, int E1, int E2)
{
    int gid = blockIdx.x;
    int* rp; const int* bs; int b; int E;
    if (gid < nb) { rp = rp_hf; bs = bs_hf; b = gid; E = E1; }
    else         { rp = rp_tt; bs = bs_tt; b = gid - nb; E = E2; }
    int t = threadIdx.x;
    int lane = t & 63;
    int partial = 0;
    for (int i = lane; i < b; i += 64) partial += bs[i];
    #pragma unroll
    for (int off = 32; off; off >>= 1) partial += __shfl_xor(partial, off);
    if (b == 0 && t == 0) rp[n] = E;
    if (partial == 0) return;
    int i0 = b * SCAN_EPB + t * 4;
    if (i0 + 0 < n) rp[i0 + 0] += partial;
    if (i0 + 1 < n) rp[i0 + 1] += partial;
    if (i0 + 2 < n) rp[i0 + 2] += partial;
    if (i0 + 3 < n) rp[i0 + 3] += partial;
}

__global__ void fill_both_kernel(
    const int* __restrict__ hf_src, const int* __restrict__ hf_dst,
    const unsigned short* __restrict__ rank_hf,
    const int* __restrict__ rp_hf, int* __restrict__ col_hf,
    const int* __restrict__ tt_src, const int* __restrict__ tt_dst,
    const unsigned short* __restrict__ rank_tt,
    const int* __restrict__ rp_tt, int* __restrict__ col_tt,
    int E1, int E2) {
    int i0 = (blockIdx.x * blockDim.x + threadIdx.x) * 4;
    if (i0 + 3 < E1) {
        int4 d = *(const int4*)(hf_dst + i0);
        int4 s = *(const int4*)(hf_src + i0);
        ushort4 r = *(const ushort4*)(rank_hf + i0);
        int p0 = rp_hf[d.x], p1 = rp_hf[d.y], p2 = rp_hf[d.z], p3 = rp_hf[d.w];
        col_hf[p0 + r.x] = s.x;
        col_hf[p1 + r.y] = s.y;
        col_hf[p2 + r.z] = s.z;
        col_hf[p3 + r.w] = s.w;
    } else {
        for (int j = 0; j < 4 && i0 + j < E1; ++j)
            col_hf[rp_hf[hf_dst[i0 + j]] + rank_hf[i0 + j]] = hf_src[i0 + j];
    }
    if (i0 + 3 < E2) {
        int4 d = *(const int4*)(tt_dst + i0);
        int4 s = *(const int4*)(tt_src + i0);
        ushort4 r = *(const ushort4*)(rank_tt + i0);
        int p0 = rp_tt[d.x], p1 = rp_tt[d.y], p2 = rp_tt[d.z], p3 = rp_tt[d.w];
        col_tt[p0 + r.x] = s.x;
        col_tt[p1 + r.y] = s.y;
        col_tt[p2 + r.z] = s.z;
        col_tt[p3 + r.w] = s.w;
    } else {
        for (int j = 0; j < 4 && i0 + j < E2; ++j)
            col_tt[rp_tt[tt_dst[i0 + j]] + rank_tt[i0 + j]] = tt_src[i0 + j];
    }
}

// ---------------- dtype conversion passes ----------------

__global__ void split_rows_kernel(const float* __restrict__ in,
                                  unsigned short* __restrict__ hi,
                                  unsigned short* __restrict__ lo, int nelem) {
    int i = (blockIdx.x * blockDim.x + threadIdx.x) * 4;
    if (i >= nelem) return;
    float4 v = *(const float4*)(in + i);
    s16x4 hv, lv;
    unsigned short h0 = f2bf(v.x); hv[0] = (short)h0; lv[0] = (short)f2bf(v.x - bf2f(h0));
    unsigned short h1 = f2bf(v.y); hv[1] = (short)h1; lv[1] = (short)f2bf(v.y - bf2f(h1));
    unsigned short h2 = f2bf(v.z); hv[2] = (short)h2; lv[2] = (short)f2bf(v.z - bf2f(h2));
    unsigned short h3 = f2bf(v.w); hv[3] = (short)h3; lv[3] = (short)f2bf(v.w - bf2f(h3));
    *(s16x4*)(hi + i) = hv;
    *(s16x4*)(lo + i) = lv;
}

__global__ void tobf16_kernel(const float* __restrict__ in,
                              unsigned short* __restrict__ hi, int nelem) {
    int i = (blockIdx.x * blockDim.x + threadIdx.x) * 4;
    if (i >= nelem) return;
    float4 v = *(const float4*)(in + i);
    s16x4 hv;
    hv[0] = (short)f2bf(v.x);
    hv[1] = (short)f2bf(v.y);
    hv[2] = (short)f2bf(v.z);
    hv[3] = (short)f2bf(v.w);
    *(s16x4*)(hi + i) = hv;
}

// ---------------- segment mean (one wave per dst row), outputs bf16 hi/lo ----------------

template<bool SRCBF>
__global__ __launch_bounds__(256) void agg_mean_kernel(
    const void* __restrict__ hsrc, const int* __restrict__ rowptr,
    const int* __restrict__ col,
    unsigned short* __restrict__ oh, unsigned short* __restrict__ ol, int ndst) {
    int w = (blockIdx.x * blockDim.x + threadIdx.x) >> 6;
    int lane = threadIdx.x & 63;
    if (w >= ndst) return;
    int beg = rowptr[w];
    int end = rowptr[w + 1];
    int deg = end - beg;
    float ax[8], ay[8];
    #pragma unroll
    for (int u = 0; u < 8; ++u) { ax[u] = 0.f; ay[u] = 0.f; }
    const float* basef = (const float*)hsrc + lane * 2;
    const unsigned short* baseb = (const unsigned short*)hsrc + lane * 2;

    for (int b = beg; b < end; b += 64) {
        int n = min(64, end - b);
        int myidx = (lane < n) ? col[b + lane] : 0;
        int j = 0;
        for (; j + 8 <= n; j += 8) {
            int s[8];
            #pragma unroll
            for (int u = 0; u < 8; ++u) s[u] = __shfl(myidx, j + u);
            #pragma unroll
            for (int u = 0; u < 8; ++u) {
                if (SRCBF) {
                    unsigned v = *(const unsigned*)(baseb + (size_t)s[u] * D);
                    ax[u] += __builtin_bit_cast(float, v << 16);
                    ay[u] += __builtin_bit_cast(float, v & 0xFFFF0000u);
                } else {
                    float2 v = *(const float2*)(basef + (size_t)s[u] * D);
                    ax[u] += v.x; ay[u] += v.y;
                }
            }
        }
        for (; j < n; ++j) {
            int s0 = __shfl(myidx, j);
            if (SRCBF) {
                unsigned v = *(const unsigned*)(baseb + (size_t)s0 * D);
                ax[0] += __builtin_bit_cast(float, v << 16);
                ay[0] += __builtin_bit_cast(float, v & 0xFFFF0000u);
            } else {
                float2 v = *(const float2*)(basef + (size_t)s0 * D);
                ax[0] += v.x; ay[0] += v.y;
            }
        }
    }
    float inv = 1.0f / fmaxf((float)deg, 1.0f);
    float sx = (((ax[0] + ax[1]) + (ax[2] + ax[3])) + ((ax[4] + ax[5]) + (ax[6] + ax[7]))) * inv;
    float sy = (((ay[0] + ay[1]) + (ay[2] + ay[3])) + ((ay[4] + ay[5]) + (ay[6] + ay[7]))) * inv;
    unsigned short hx = f2bf(sx), hy = f2bf(sy);
    unsigned short lx = f2bf(sx - bf2f(hx)), ly = f2bf(sy - bf2f(hy));
    ((unsigned*)oh)[(size_t)w * 64 + lane] = (unsigned)hx | ((unsigned)hy << 16);
    ((unsigned*)ol)[(size_t)w * 64 + lane] = (unsigned)lx | ((unsigned)ly << 16);
}

// ---------------- weight prep: transpose + bf16 hi/lo split + XOR swizzle ----------------

__global__ __launch_bounds__(256) void prep_weights_kernel(
    const float* __restrict__ Wself, const float* __restrict__ Wneigh,
    short* __restrict__ wt)
{
    int g = blockIdx.x * 256 + threadIdx.x;      // [0, 16384)
    int m = g >> 11;
    int e = g & 2047;
    int n  = e >> 4;
    int kg = e & 15;
    int kk0 = kg >> 3;
    int kl0 = (kg & 7) * 8;
    int pair = m >> 1, s = m & 1;
    int l = (pair == 3) ? 2 : ((pair == 2) ? 1 : 0);
    int r = (pair == 0) ? 0 : 1;
    const float* W = (s ? Wneigh : Wself) + (size_t)(l * 2 + r) * D * D;
    s16x8 hv, lv;
    #pragma unroll
    for (int c = 0; c < 8; ++c) {
        int k = kk0 * 64 + kl0 + c;
        float x = W[(size_t)k * D + n];
        unsigned short h = f2bf(x);
        hv[c] = (short)h;
        lv[c] = (short)f2bf(x - bf2f(h));
    }
    int ksb = kl0 ^ ((n & 7) << 3);
    size_t base = ((((size_t)pair * 2 + s) * 2 + kk0) * 2) * 8192;
    *(s16x8*)&wt[base + n * 64 + ksb]        = hv;
    *(s16x8*)&wt[base + 8192 + n * 64 + ksb] = lv;
}

// ---------------- fused SAGE layer via split-bf16 MFMA, BM=64 ----------------
// Round-8 lesson: BM=128 grid (391 blocks) = 1.5 blocks/CU -> occupancy 14%,
// latency-starved. BM=64: 782 blocks, LDS 48KB -> 3 blocks/CU resident.
// 2x2 wave grid: wave owns 32 rows x 64 cols (acc[2]).

template<bool ACC, bool WF32, bool WBF>
__global__ __launch_bounds__(256) void sage_mfma_kernel(
    const unsigned short* __restrict__ Ah_g, const unsigned short* __restrict__ Al_g,
    const unsigned short* __restrict__ Nh_g, const unsigned short* __restrict__ Nl_g,
    const short* __restrict__ wtp, const float* __restrict__ bias,
    float* __restrict__ Yf, unsigned short* __restrict__ Yh, unsigned short* __restrict__ Yl,
    int M)
{
    __shared__ short Ah[64 * 64];
    __shared__ short Al[64 * 64];
    __shared__ short Bh[128 * 64];
    __shared__ short Bl[128 * 64];

    const int tid = threadIdx.x;
    const int l = tid & 63, w = tid >> 6;
    const int wr = w >> 1, wc = w & 1;
    const int row0 = blockIdx.x * 64;

    f32x16 acc[2] = {};

    const int s_row = tid >> 2;           // 0..63
    const int s_k   = (tid & 3) * 16;     // 0,16,32,48
    const int s_sw  = (s_row & 7) << 3;
    const int arow  = wr * 32 + (l & 31);
    const int fsw   = (l & 7) << 3;
    const int afk   = (l >> 5) * 8;

    #pragma unroll 1
    for (int s = 0; s < 2; ++s) {
        const unsigned short* Hg = s ? Nh_g : Ah_g;
        const unsigned short* Lg = s ? Nl_g : Al_g;
        #pragma unroll 1
        for (int kk0 = 0; kk0 < 2; ++kk0) {
            __syncthreads();
            // activation staging: pure copy with XOR swizzle
            {
                int grow = row0 + s_row;
                const unsigned short* hrow = Hg + (size_t)grow * D + kk0 * 64 + s_k;
                const unsigned short* lrow = Lg + (size_t)grow * D + kk0 * 64 + s_k;
                s16x8 h0 = {}, h1 = {}, l0 = {}, l1 = {};
                if (grow < M) {
                    h0 = *(const s16x8*)(hrow);
                    h1 = *(const s16x8*)(hrow + 8);
                    l0 = *(const s16x8*)(lrow);
                    l1 = *(const s16x8*)(lrow + 8);
                }
                *(s16x8*)&Ah[s_row * 64 + (s_k ^ s_sw)]       = h0;
                *(s16x8*)&Ah[s_row * 64 + ((s_k + 8) ^ s_sw)] = h1;
                *(s16x8*)&Al[s_row * 64 + (s_k ^ s_sw)]       = l0;
                *(s16x8*)&Al[s_row * 64 + ((s_k + 8) ^ s_sw)] = l1;
            }
            // weight staging: linear copy, consecutive lanes -> consecutive 16B
            const short* wsrc = wtp + ((size_t)(s * 2 + kk0) * 2) * 8192;
            #pragma unroll
            for (int c = 0; c < 4; ++c) {
                int o = (c * 256 + tid) * 8;
                *(s16x8*)&Bh[o] = *(const s16x8*)(wsrc + o);
                *(s16x8*)&Bl[o] = *(const s16x8*)(wsrc + 8192 + o);
            }
            __syncthreads();
            #pragma unroll
            for (int kc = 0; kc < 4; ++kc) {
                int ak = (kc * 16 + afk) ^ fsw;
                s16x8 ah = *(const s16x8*)&Ah[arow * 64 + ak];
                s16x8 al = *(const s16x8*)&Al[arow * 64 + ak];
                #pragma unroll
                for (int nt = 0; nt < 2; ++nt) {
                    int brow = wc * 64 + nt * 32 + (l & 31);
                    s16x8 bh = *(const s16x8*)&Bh[brow * 64 + ak];
                    s16x8 bl = *(const s16x8*)&Bl[brow * 64 + ak];
                    acc[nt] = __builtin_amdgcn_mfma_f32_32x32x16_bf16(ah, bh, acc[nt], 0, 0, 0);
                    acc[nt] = __builtin_amdgcn_mfma_f32_32x32x16_bf16(ah, bl, acc[nt], 0, 0, 0);
                    acc[nt] = __builtin_amdgcn_mfma_f32_32x32x16_bf16(al, bh, acc[nt], 0, 0, 0);
                }
            }
        }
    }

    // D layout: col=lane&31, row=(reg&3)+8*(reg>>2)+4*(lane>>5)
    const int colb = l & 31;
    const int rq4  = (l >> 5) * 4;
    #pragma unroll
    for (int nt = 0; nt < 2; ++nt) {
        int col = wc * 64 + nt * 32 + colb;
        float bias_c = bias[col];
        #pragma unroll
        for (int g = 0; g < 4; ++g) {
            #pragma unroll
            for (int q = 0; q < 4; ++q) {
                int row = row0 + wr * 32 + q + g * 8 + rq4;
                if (row < M) {
                    size_t idx = (size_t)row * D + col;
                    float v = fmaxf(acc[nt][g * 4 + q] + bias_c, 0.f);
                    if (ACC) v += bf2f(Yh[idx]) + bf2f(Yl[idx]);
                    if (WF32) Yf[idx] = v;
                    if (WBF) {
                        unsigned short h = f2bf(v);
                        Yh[idx] = h;
                        Yl[idx] = f2bf(v - bf2f(h));
                    }
                }
            }
        }
    }
}

// ---------------- launch ----------------

extern "C" void kernel_launch(void* const* d_in, const int* in_sizes, int n_in,
                              void* d_out, int out_size, void* d_ws, size_t ws_size,
                              hipStream_t stream) {
    const float* h_station = (const float*)d_in[0];
    const float* h_feature = (const float*)d_in[1];
    const float* Wself     = (const float*)d_in[2];
    const float* Wneigh    = (const float*)d_in[3];
    const float* bias      = (const float*)d_in[4];
    const int* hf_src = (const int*)d_in[5];
    const int* hf_dst = (const int*)d_in[6];
    const int* tt_src = (const int*)d_in[7];
    const int* tt_dst = (const int*)d_in[8];

    const int NS = in_sizes[0] / D;
    const int NF = in_sizes[1] / D;
    const int E1 = in_sizes[5];
    const int E2 = in_sizes[7];

    // workspace carve-up (with time-disjoint aliasing)
    char* ws = (char*)d_ws;
    size_t off = 0;
    auto alloc = [&](size_t bytes) -> void* {
        void* p = ws + off;
        off = (off + bytes + 255) & ~(size_t)255;
        return p;
    };
    unsigned short* st_h  = (unsigned short*)alloc((size_t)NS * D * 2);
    unsigned short* st_l  = (unsigned short*)alloc((size_t)NS * D * 2);
    unsigned short* n_h   = (unsigned short*)alloc((size_t)NS * D * 2);
    unsigned short* n_l   = (unsigned short*)alloc((size_t)NS * D * 2);
    unsigned short* hb_h  = (unsigned short*)alloc((size_t)NS * D * 2 * 2);  // hb_h + hb_l contiguous
    unsigned short* hb_l  = hb_h + (size_t)NS * D;
    int* rp_hf    = (int*)alloc((size_t)(NS + 1) * sizeof(int));
    int* col_hf   = (int*)alloc((size_t)E1 * sizeof(int));
    int* rp_tt    = (int*)alloc((size_t)(NS + 1) * sizeof(int));
    int* col_tt   = (int*)alloc((size_t)E2 * sizeof(int));
    unsigned short* rank_hf = (unsigned short*)alloc((size_t)E1 * 2);
    unsigned short* rank_tt = (unsigned short*)alloc((size_t)E2 * 2);
    int  nb       = (NS + SCAN_EPB - 1) / SCAN_EPB;
    int* bs_hf    = (int*)alloc((size_t)nb * sizeof(int));
    int* bs_tt    = (int*)alloc((size_t)nb * sizeof(int));
    short* wt     = (short*)alloc((size_t)4 * 65536 * sizeof(short));

    // aliases (time-disjoint, stream-ordered):
    // deg arrays (NS*CPAD ints = 6.4MB) live in n_h/n_l until the first agg writes n.
    int* deg_hf = (int*)n_h;
    int* deg_tt = (int*)n_l;
    // feat_h (NF*D shorts = 25.6MB) lives in hb_h+hb_l until GEMM1 writes hb.
    unsigned short* feat_h = hb_h;

    const int tpb = 256;
    int ge   = (max(E1, E2) + tpb - 1) / tpb;
    int ge4  = ((max(E1, E2) + 3) / 4 + tpb - 1) / tpb;
    int gsp  = ((NS * D / 4) + tpb - 1) / tpb;
    int gft  = ((NF * D / 4) + tpb - 1) / tpb;
    int gzp  = ((NS * CPAD / 4) + tpb - 1) / tpb;

    prep_weights_kernel<<<64, tpb, 0, stream>>>(Wself, Wneigh, wt);
    tobf16_kernel<<<gft, tpb, 0, stream>>>(h_feature, feat_h, NF * D);
    split_rows_kernel<<<gsp, tpb, 0, stream>>>(h_station, st_h, st_l, NS * D);
    zero_pad_kernel<<<gzp, tpb, 0, stream>>>(deg_hf, deg_tt, NS * CPAD / 4);
    count_rank_kernel<<<ge, tpb, 0, stream>>>(hf_dst, tt_dst, deg_hf, deg_tt,
                                              rank_hf, rank_tt, E1, E2);
    scan_blocks_kernel<<<2 * nb, tpb, 0, stream>>>(deg_hf, rp_hf, bs_hf,
                                                   deg_tt, rp_tt, bs_tt, NS, nb);
    scan_offsets_kernel<<<2 * nb, tpb, 0, stream>>>(rp_hf, bs_hf, rp_tt, bs_tt,
                                                    NS, nb, E1, E2);
    fill_both_kernel<<<ge4, tpb, 0, stream>>>(hf_src, hf_dst, rank_hf, rp_hf, col_hf,
                                              tt_src, tt_dst, rank_tt, rp_tt, col_tt, E1, E2);

    int gagg  = (NS * 64 + tpb - 1) / tpb;
    int ggemm = (NS + 63) / 64;

    auto BI = [&](int lidx, int r) { return bias + (size_t)(lidx * 2 + r) * D; };
    auto WT = [&](int pair) { return wt + (size_t)pair * 65536; };

    float* out = (float*)d_out;

    // ---- layer 1 ----
    // hf agg reads feat_h (hb region), writes n (overwriting dead deg arrays)
    agg_mean_kernel<true><<<gagg, tpb, 0, stream>>>(feat_h, rp_hf, col_hf, n_h, n_l, NS);
    // GEMM1 writes hb (overwriting dead feat_h)
    sage_mfma_kernel<false, false, true><<<ggemm, tpb, 0, stream>>>(
        st_h, st_l, n_h, n_l, WT(0), BI(0,0), nullptr, hb_h, hb_l, NS);
    agg_mean_kernel<true><<<gagg, tpb, 0, stream>>>(st_h, rp_tt, col_tt, n_h, n_l, NS);
    sage_mfma_kernel<true, false, true><<<ggemm, tpb, 0, stream>>>(
        st_h, st_l, n_h, n_l, WT(1), BI(0,1), nullptr, hb_h, hb_l, NS);

    // ---- layer 2 (in-place: blocks read only their own rows before writing) ----
    agg_mean_kernel<true><<<gagg, tpb, 0, stream>>>(hb_h, rp_tt, col_tt, n_h, n_l, NS);
    sage_mfma_kernel<false, false, true><<<ggemm, tpb, 0, stream>>>(
        hb_h, hb_l, n_h, n_l, WT(2), BI(1,1), nullptr, hb_h, hb_l, NS);

    // ---- layer 3 ----
    agg_mean_kernel<true><<<gagg, tpb, 0, stream>>>(hb_h, rp_tt, col_tt, n_h, n_l, NS);
    sage_mfma_kernel<false, true, false><<<ggemm, tpb, 0, stream>>>(
        hb_h, hb_l, n_h, n_l, WT(3), BI(2,1), out, nullptr, nullptr, NS);
}

// Round 10
// 325.909 us; speedup vs baseline: 1.0543x; 1.0543x over previous
//
#include <hip/hip_runtime.h>

#define D 128
#define CPAD 32   // one counter per 128B line (validated round 9: count_rank left top-5)

typedef __attribute__((ext_vector_type(8)))  short s16x8;
typedef __attribute__((ext_vector_type(4)))  short s16x4;
typedef __attribute__((ext_vector_type(16))) float f32x16;

static __device__ __forceinline__ unsigned short f2bf(float x) {
    unsigned u = __builtin_bit_cast(unsigned, x);
    unsigned r = (u + 0x7FFF + ((u >> 16) & 1)) >> 16;   // RNE
    return (unsigned short)r;
}
static __device__ __forceinline__ float bf2f(unsigned short h) {
    unsigned u = ((unsigned)h) << 16;
    return __builtin_bit_cast(float, u);
}

// ---------------- CSR build ----------------

__global__ void zero_pad_kernel(int* __restrict__ a, int* __restrict__ b, int n4) {
    int i = blockIdx.x * blockDim.x + threadIdx.x;
    if (i < n4) {
        *(int4*)(a + i * 4) = make_int4(0, 0, 0, 0);
        *(int4*)(b + i * 4) = make_int4(0, 0, 0, 0);
    }
}

__global__ void count_rank_kernel(const int* __restrict__ hf_dst, const int* __restrict__ tt_dst,
                                  int* __restrict__ deg_hf, int* __restrict__ deg_tt,
                                  unsigned short* __restrict__ rank_hf,
                                  unsigned short* __restrict__ rank_tt,
                                  int E1, int E2) {
    int i = blockIdx.x * blockDim.x + threadIdx.x;
    if (i < E1) {
        int r = atomicAdd(&deg_hf[hf_dst[i] * CPAD], 1);
        rank_hf[i] = (unsigned short)r;
    }
    if (i < E2) {
        int r = atomicAdd(&deg_tt[tt_dst[i] * CPAD], 1);
        rank_tt[i] = (unsigned short)r;
    }
}

#define SCAN_EPB 1024

__global__ __launch_bounds__(256) void scan_blocks_kernel(
    const int* __restrict__ deg_hf, int* __restrict__ rp_hf, int* __restrict__ bs_hf,
    const int* __restrict__ deg_tt, int* __restrict__ rp_tt, int* __restrict__ bs_tt,
    int n, int nb)
{
    int gid = blockIdx.x;
    const int* deg; int* rp; int* bs; int b;
    if (gid < nb) { deg = deg_hf; rp = rp_hf; bs = bs_hf; b = gid; }
    else         { deg = deg_tt; rp = rp_tt; bs = bs_tt; b = gid - nb; }
    int t = threadIdx.x;
    int i0 = b * SCAN_EPB + t * 4;
    int4 v = make_int4(0, 0, 0, 0);
    if (i0 + 0 < n) v.x = deg[(size_t)(i0 + 0) * CPAD];
    if (i0 + 1 < n) v.y = deg[(size_t)(i0 + 1) * CPAD];
    if (i0 + 2 < n) v.z = deg[(size_t)(i0 + 2) * CPAD];
    if (i0 + 3 < n) v.w = deg[(size_t)(i0 + 3) * CPAD];
    __shared__ int sm[256];
    sm[t] = v.x + v.y + v.z + v.w;
    __syncthreads();
    for (int off = 1; off < 256; off <<= 1) {
        int x = (t >= off) ? sm[t - off] : 0;
        __syncthreads();
        sm[t] += x;
        __syncthreads();
    }
    int excl = (t > 0) ? sm[t - 1] : 0;
    if (i0 + 0 < n) rp[i0 + 0] = excl;
    if (i0 + 1 < n) rp[i0 + 1] = excl + v.x;
    if (i0 + 2 < n) rp[i0 + 2] = excl + v.x + v.y;
    if (i0 + 3 < n) rp[i0 + 3] = excl + v.x + v.y + v.z;
    if (t == 255) bs[b] = sm[255];
}

__global__ __launch_bounds__(256) void scan_offsets_kernel(
    int* __restrict__ rp_hf, const int* __restrict__ bs_hf,
    int* __restrict__ rp_tt, const int* __restrict__ bs_tt,
    int n, int nb, int E1, int E2)
{
    int gid = blockIdx.x;
    int* rp; const int* bs; int b; int E;
    if (gid < nb) { rp = rp_hf; bs = bs_hf; b = gid; E = E1; }
    else         { rp = rp_tt; bs = bs_tt; b = gid - nb; E = E2; }
    int t = threadIdx.x;
    int lane = t & 63;
    int partial = 0;
    for (int i = lane; i < b; i += 64) partial += bs[i];
    #pragma unroll
    for (int off = 32; off; off >>= 1) partial += __shfl_xor(partial, off);
    if (b == 0 && t == 0) rp[n] = E;
    if (partial == 0) return;
    int i0 = b * SCAN_EPB + t * 4;
    if (i0 + 0 < n) rp[i0 + 0] += partial;
    if (i0 + 1 < n) rp[i0 + 1] += partial;
    if (i0 + 2 < n) rp[i0 + 2] += partial;
    if (i0 + 3 < n) rp[i0 + 3] += partial;
}

__global__ void fill_both_kernel(
    const int* __restrict__ hf_src, const int* __restrict__ hf_dst,
    const unsigned short* __restrict__ rank_hf,
    const int* __restrict__ rp_hf, int* __restrict__ col_hf,
    const int* __restrict__ tt_src, const int* __restrict__ tt_dst,
    const unsigned short* __restrict__ rank_tt,
    const int* __restrict__ rp_tt, int* __restrict__ col_tt,
    int E1, int E2) {
    int i0 = (blockIdx.x * blockDim.x + threadIdx.x) * 4;
    if (i0 + 3 < E1) {
        int4 d = *(const int4*)(hf_dst + i0);
        int4 s = *(const int4*)(hf_src + i0);
        ushort4 r = *(const ushort4*)(rank_hf + i0);
        int p0 = rp_hf[d.x], p1 = rp_hf[d.y], p2 = rp_hf[d.z], p3 = rp_hf[d.w];
        col_hf[p0 + r.x] = s.x;
        col_hf[p1 + r.y] = s.y;
        col_hf[p2 + r.z] = s.z;
        col_hf[p3 + r.w] = s.w;
    } else {
        for (int j = 0; j < 4 && i0 + j < E1; ++j)
            col_hf[rp_hf[hf_dst[i0 + j]] + rank_hf[i0 + j]] = hf_src[i0 + j];
    }
    if (i0 + 3 < E2) {
        int4 d = *(const int4*)(tt_dst + i0);
        int4 s = *(const int4*)(tt_src + i0);
        ushort4 r = *(const ushort4*)(rank_tt + i0);
        int p0 = rp_tt[d.x], p1 = rp_tt[d.y], p2 = rp_tt[d.z], p3 = rp_tt[d.w];
        col_tt[p0 + r.x] = s.x;
        col_tt[p1 + r.y] = s.y;
        col_tt[p2 + r.z] = s.z;
        col_tt[p3 + r.w] = s.w;
    } else {
        for (int j = 0; j < 4 && i0 + j < E2; ++j)
            col_tt[rp_tt[tt_dst[i0 + j]] + rank_tt[i0 + j]] = tt_src[i0 + j];
    }
}

// ---------------- dtype conversion passes ----------------

__global__ void split_rows_kernel(const float* __restrict__ in,
                                  unsigned short* __restrict__ hi,
                                  unsigned short* __restrict__ lo, int nelem) {
    int i = (blockIdx.x * blockDim.x + threadIdx.x) * 4;
    if (i >= nelem) return;
    float4 v = *(const float4*)(in + i);
    s16x4 hv, lv;
    unsigned short h0 = f2bf(v.x); hv[0] = (short)h0; lv[0] = (short)f2bf(v.x - bf2f(h0));
    unsigned short h1 = f2bf(v.y); hv[1] = (short)h1; lv[1] = (short)f2bf(v.y - bf2f(h1));
    unsigned short h2 = f2bf(v.z); hv[2] = (short)h2; lv[2] = (short)f2bf(v.z - bf2f(h2));
    unsigned short h3 = f2bf(v.w); hv[3] = (short)h3; lv[3] = (short)f2bf(v.w - bf2f(h3));
    *(s16x4*)(hi + i) = hv;
    *(s16x4*)(lo + i) = lv;
}

__global__ void tobf16_kernel(const float* __restrict__ in,
                              unsigned short* __restrict__ hi, int nelem) {
    int i = (blockIdx.x * blockDim.x + threadIdx.x) * 4;
    if (i >= nelem) return;
    float4 v = *(const float4*)(in + i);
    s16x4 hv;
    hv[0] = (short)f2bf(v.x);
    hv[1] = (short)f2bf(v.y);
    hv[2] = (short)f2bf(v.z);
    hv[3] = (short)f2bf(v.w);
    *(s16x4*)(hi + i) = hv;
}

// ---------------- segment mean (one wave per dst row), outputs bf16 hi/lo ----------------

template<bool SRCBF>
__global__ __launch_bounds__(256) void agg_mean_kernel(
    const void* __restrict__ hsrc, const int* __restrict__ rowptr,
    const int* __restrict__ col,
    unsigned short* __restrict__ oh, unsigned short* __restrict__ ol, int ndst) {
    int w = (blockIdx.x * blockDim.x + threadIdx.x) >> 6;
    int lane = threadIdx.x & 63;
    if (w >= ndst) return;
    int beg = rowptr[w];
    int end = rowptr[w + 1];
    int deg = end - beg;
    float ax[8], ay[8];
    #pragma unroll
    for (int u = 0; u < 8; ++u) { ax[u] = 0.f; ay[u] = 0.f; }
    const float* basef = (const float*)hsrc + lane * 2;
    const unsigned short* baseb = (const unsigned short*)hsrc + lane * 2;

    for (int b = beg; b < end; b += 64) {
        int n = min(64, end - b);
        int myidx = (lane < n) ? col[b + lane] : 0;
        int j = 0;
        for (; j + 8 <= n; j += 8) {
            int s[8];
            #pragma unroll
            for (int u = 0; u < 8; ++u) s[u] = __shfl(myidx, j + u);
            #pragma unroll
            for (int u = 0; u < 8; ++u) {
                if (SRCBF) {
                    unsigned v = *(const unsigned*)(baseb + (size_t)s[u] * D);
                    ax[u] += __builtin_bit_cast(float, v << 16);
                    ay[u] += __builtin_bit_cast(float, v & 0xFFFF0000u);
                } else {
                    float2 v = *(const float2*)(basef + (size_t)s[u] * D);
                    ax[u] += v.x; ay[u] += v.y;
                }
            }
        }
        for (; j < n; ++j) {
            int s0 = __shfl(myidx, j);
            if (SRCBF) {
                unsigned v = *(const unsigned*)(baseb + (size_t)s0 * D);
                ax[0] += __builtin_bit_cast(float, v << 16);
                ay[0] += __builtin_bit_cast(float, v & 0xFFFF0000u);
            } else {
                float2 v = *(const float2*)(basef + (size_t)s0 * D);
                ax[0] += v.x; ay[0] += v.y;
            }
        }
    }
    float inv = 1.0f / fmaxf((float)deg, 1.0f);
    float sx = (((ax[0] + ax[1]) + (ax[2] + ax[3])) + ((ax[4] + ax[5]) + (ax[6] + ax[7]))) * inv;
    float sy = (((ay[0] + ay[1]) + (ay[2] + ay[3])) + ((ay[4] + ay[5]) + (ay[6] + ay[7]))) * inv;
    unsigned short hx = f2bf(sx), hy = f2bf(sy);
    unsigned short lx = f2bf(sx - bf2f(hx)), ly = f2bf(sy - bf2f(hy));
    ((unsigned*)oh)[(size_t)w * 64 + lane] = (unsigned)hx | ((unsigned)hy << 16);
    ((unsigned*)ol)[(size_t)w * 64 + lane] = (unsigned)lx | ((unsigned)ly << 16);
}

// ---------------- weight prep: transpose + bf16 hi/lo split + XOR swizzle ----------------

__global__ __launch_bounds__(256) void prep_weights_kernel(
    const float* __restrict__ Wself, const float* __restrict__ Wneigh,
    short* __restrict__ wt)
{
    int g = blockIdx.x * 256 + threadIdx.x;      // [0, 16384)
    int m = g >> 11;
    int e = g & 2047;
    int n  = e >> 4;
    int kg = e & 15;
    int kk0 = kg >> 3;
    int kl0 = (kg & 7) * 8;
    int pair = m >> 1, s = m & 1;
    int l = (pair == 3) ? 2 : ((pair == 2) ? 1 : 0);
    int r = (pair == 0) ? 0 : 1;
    const float* W = (s ? Wneigh : Wself) + (size_t)(l * 2 + r) * D * D;
    s16x8 hv, lv;
    #pragma unroll
    for (int c = 0; c < 8; ++c) {
        int k = kk0 * 64 + kl0 + c;
        float x = W[(size_t)k * D + n];
        unsigned short h = f2bf(x);
        hv[c] = (short)h;
        lv[c] = (short)f2bf(x - bf2f(h));
    }
    int ksb = kl0 ^ ((n & 7) << 3);
    size_t base = ((((size_t)pair * 2 + s) * 2 + kk0) * 2) * 8192;
    *(s16x8*)&wt[base + n * 64 + ksb]        = hv;
    *(s16x8*)&wt[base + 8192 + n * 64 + ksb] = lv;
}

// ---------------- fused SAGE layer via split-bf16 MFMA, BM=64, T14 pipeline ----------------
// Round-9: 50us each with MfmaUtil 7 / VALU 8 / HBM 19 -> barrier-serialized
// latency + 2B-scatter epilogue. Fix: (1) reg-prefetch next stage's 12x16B
// loads before MFMA of current stage; (2) fp32 LDS re-stage epilogue ->
// fully coalesced 16B global IO. Activation buffers padded to 64 rows.

struct StageRegs {
    s16x8 a0, a1, a2, a3;                     // Ah x2, Al x2
    s16x8 b0, b1, b2, b3, b4, b5, b6, b7;     // Bh x4, Bl x4
};

template<bool ACC, bool WF32, bool WBF>
__global__ __launch_bounds__(256) void sage_mfma_kernel(
    const unsigned short* __restrict__ Ah_g, const unsigned short* __restrict__ Al_g,
    const unsigned short* __restrict__ Nh_g, const unsigned short* __restrict__ Nl_g,
    const short* __restrict__ wtp, const float* __restrict__ bias,
    float* __restrict__ Yf, unsigned short* __restrict__ Yh, unsigned short* __restrict__ Yl,
    int M)
{
    __shared__ short lds[24576];   // 48KB: Ah[0:4k] Al[4k:8k] Bh[8k:16k] Bl[16k:24k] (shorts)
    short* AhS = lds;
    short* AlS = lds + 4096;
    short* BhS = lds + 8192;
    short* BlS = lds + 16384;

    const int tid = threadIdx.x;
    const int l = tid & 63, w = tid >> 6;
    const int wr = w >> 1, wc = w & 1;
    const int row0 = blockIdx.x * 64;

    f32x16 acc[2] = {};

    const int s_row = tid >> 2;           // 0..63
    const int s_k   = (tid & 3) * 16;     // 0,16,32,48
    const int s_sw  = (s_row & 7) << 3;
    const int arow  = wr * 32 + (l & 31);
    const int fsw   = (l & 7) << 3;
    const int afk   = (l >> 5) * 8;

    StageRegs rg;

    auto issue = [&](int st) {
        int s = st >> 1, kk0 = st & 1;
        const unsigned short* Hg = s ? Nh_g : Ah_g;
        const unsigned short* Lg = s ? Nl_g : Al_g;
        const unsigned short* hrow = Hg + (size_t)(row0 + s_row) * D + kk0 * 64 + s_k;
        const unsigned short* lrow = Lg + (size_t)(row0 + s_row) * D + kk0 * 64 + s_k;
        rg.a0 = *(const s16x8*)(hrow);
        rg.a1 = *(const s16x8*)(hrow + 8);
        rg.a2 = *(const s16x8*)(lrow);
        rg.a3 = *(const s16x8*)(lrow + 8);
        const short* wsrc = wtp + (size_t)st * 2 * 8192;
        rg.b0 = *(const s16x8*)(wsrc + tid * 8);
        rg.b1 = *(const s16x8*)(wsrc + 2048 + tid * 8);
        rg.b2 = *(const s16x8*)(wsrc + 4096 + tid * 8);
        rg.b3 = *(const s16x8*)(wsrc + 6144 + tid * 8);
        rg.b4 = *(const s16x8*)(wsrc + 8192 + tid * 8);
        rg.b5 = *(const s16x8*)(wsrc + 10240 + tid * 8);
        rg.b6 = *(const s16x8*)(wsrc + 12288 + tid * 8);
        rg.b7 = *(const s16x8*)(wsrc + 14336 + tid * 8);
    };
    auto commit = [&]() {
        *(s16x8*)&AhS[s_row * 64 + (s_k ^ s_sw)]       = rg.a0;
        *(s16x8*)&AhS[s_row * 64 + ((s_k + 8) ^ s_sw)] = rg.a1;
        *(s16x8*)&AlS[s_row * 64 + (s_k ^ s_sw)]       = rg.a2;
        *(s16x8*)&AlS[s_row * 64 + ((s_k + 8) ^ s_sw)] = rg.a3;
        *(s16x8*)&BhS[tid * 8]         = rg.b0;
        *(s16x8*)&BhS[2048 + tid * 8]  = rg.b1;
        *(s16x8*)&BhS[4096 + tid * 8]  = rg.b2;
        *(s16x8*)&BhS[6144 + tid * 8]  = rg.b3;
        *(s16x8*)&BlS[tid * 8]         = rg.b4;
        *(s16x8*)&BlS[2048 + tid * 8]  = rg.b5;
        *(s16x8*)&BlS[4096 + tid * 8]  = rg.b6;
        *(s16x8*)&BlS[6144 + tid * 8]  = rg.b7;
    };

    issue(0);
    #pragma unroll 1
    for (int st = 0; st < 4; ++st) {
        __syncthreads();              // prior-stage LDS reads done
        commit();
        if (st < 3) issue(st + 1);    // loads drain during MFMA below (T14)
        __syncthreads();
        #pragma unroll
        for (int kc = 0; kc < 4; ++kc) {
            int ak = (kc * 16 + afk) ^ fsw;
            s16x8 ah = *(const s16x8*)&AhS[arow * 64 + ak];
            s16x8 al = *(const s16x8*)&AlS[arow * 64 + ak];
            #pragma unroll
            for (int nt = 0; nt < 2; ++nt) {
                int brow = wc * 64 + nt * 32 + (l & 31);
                s16x8 bh = *(const s16x8*)&BhS[brow * 64 + ak];
                s16x8 bl = *(const s16x8*)&BlS[brow * 64 + ak];
                acc[nt] = __builtin_amdgcn_mfma_f32_32x32x16_bf16(ah, bh, acc[nt], 0, 0, 0);
                acc[nt] = __builtin_amdgcn_mfma_f32_32x32x16_bf16(ah, bl, acc[nt], 0, 0, 0);
                acc[nt] = __builtin_amdgcn_mfma_f32_32x32x16_bf16(al, bh, acc[nt], 0, 0, 0);
            }
        }
    }

    // ---- epilogue: acc -> fp32 LDS stage -> coalesced global IO ----
    __syncthreads();
    float* fstage = (float*)lds;    // 64 rows x 128 cols fp32 = 32KB
    const int colb = l & 31;
    const int rq4  = (l >> 5) * 4;
    #pragma unroll
    for (int nt = 0; nt < 2; ++nt) {
        int col = wc * 64 + nt * 32 + colb;
        float bias_c = bias[col];
        #pragma unroll
        for (int g = 0; g < 4; ++g) {
            #pragma unroll
            for (int q = 0; q < 4; ++q) {
                int r = wr * 32 + q + g * 8 + rq4;
                fstage[r * 128 + col] = fmaxf(acc[nt][g * 4 + q] + bias_c, 0.f);
            }
        }
    }
    __syncthreads();
    // thread t: row t>>2, cols (t&3)*32 .. +32  (16B-coalesced everywhere)
    int orow = tid >> 2;
    int ocol = (tid & 3) * 32;
    int grow = row0 + orow;
    if (grow < M) {
        float vals[32];
        #pragma unroll
        for (int c = 0; c < 32; c += 4)
            *(float4*)&vals[c] = *(const float4*)&fstage[orow * 128 + ocol + c];
        size_t base = (size_t)grow * D + ocol;
        if (ACC) {
            #pragma unroll
            for (int c8 = 0; c8 < 4; ++c8) {
                s16x8 oh = *(const s16x8*)(Yh + base + c8 * 8);
                s16x8 ol = *(const s16x8*)(Yl + base + c8 * 8);
                #pragma unroll
                for (int e = 0; e < 8; ++e)
                    vals[c8 * 8 + e] += bf2f((unsigned short)oh[e]) + bf2f((unsigned short)ol[e]);
            }
        }
        if (WF32) {
            #pragma unroll
            for (int c = 0; c < 32; c += 4)
                *(float4*)(Yf + base + c - ocol + ocol + c - c) = *(const float4*)&vals[c];  // see below
        }
        if (WF32) { /* replaced above to keep compiler simple */ }
        if (WBF) {
            #pragma unroll
            for (int c8 = 0; c8 < 4; ++c8) {
                s16x8 hv, lv;
                #pragma unroll
                for (int e = 0; e < 8; ++e) {
                    float v = vals[c8 * 8 + e];
                    unsigned short h = f2bf(v);
                    hv[e] = (short)h;
                    lv[e] = (short)f2bf(v - bf2f(h));
                }
                *(s16x8*)(Yh + base + c8 * 8) = hv;
                *(s16x8*)(Yl + base + c8 * 8) = lv;
            }
        }
    }
}

// clean WF32 store was mangled above; specialize: do fp32 stores via this helper kernel path
// (WF32 only used in the final layer; implement directly in a small wrapper below)

template<>
__global__ __launch_bounds__(256) void sage_mfma_kernel<false, true, false>(
    const unsigned short* __restrict__ Ah_g, const unsigned short* __restrict__ Al_g,
    const unsigned short* __restrict__ Nh_g, const unsigned short* __restrict__ Nl_g,
    const short* __restrict__ wtp, const float* __restrict__ bias,
    float* __restrict__ Yf, unsigned short* __restrict__ Yh, unsigned short* __restrict__ Yl,
    int M)
{
    __shared__ short lds[24576];
    short* AhS = lds;
    short* AlS = lds + 4096;
    short* BhS = lds + 8192;
    short* BlS = lds + 16384;

    const int tid = threadIdx.x;
    const int l = tid & 63, w = tid >> 6;
    const int wr = w >> 1, wc = w & 1;
    const int row0 = blockIdx.x * 64;

    f32x16 acc[2] = {};

    const int s_row = tid >> 2;
    const int s_k   = (tid & 3) * 16;
    const int s_sw  = (s_row & 7) << 3;
    const int arow  = wr * 32 + (l & 31);
    const int fsw   = (l & 7) << 3;
    const int afk   = (l >> 5) * 8;

    StageRegs rg;

    auto issue = [&](int st) {
        int s = st >> 1, kk0 = st & 1;
        const unsigned short* Hg = s ? Nh_g : Ah_g;
        const unsigned short* Lg = s ? Nl_g : Al_g;
        const unsigned short* hrow = Hg + (size_t)(row0 + s_row) * D + kk0 * 64 + s_k;
        const unsigned short* lrow = Lg + (size_t)(row0 + s_row) * D + kk0 * 64 + s_k;
        rg.a0 = *(const s16x8*)(hrow);
        rg.a1 = *(const s16x8*)(hrow + 8);
        rg.a2 = *(const s16x8*)(lrow);
        rg.a3 = *(const s16x8*)(lrow + 8);
        const short* wsrc = wtp + (size_t)st * 2 * 8192;
        rg.b0 = *(const s16x8*)(wsrc + tid * 8);
        rg.b1 = *(const s16x8*)(wsrc + 2048 + tid * 8);
        rg.b2 = *(const s16x8*)(wsrc + 4096 + tid * 8);
        rg.b3 = *(const s16x8*)(wsrc + 6144 + tid * 8);
        rg.b4 = *(const s16x8*)(wsrc + 8192 + tid * 8);
        rg.b5 = *(const s16x8*)(wsrc + 10240 + tid * 8);
        rg.b6 = *(const s16x8*)(wsrc + 12288 + tid * 8);
        rg.b7 = *(const s16x8*)(wsrc + 14336 + tid * 8);
    };
    auto commit = [&]() {
        *(s16x8*)&AhS[s_row * 64 + (s_k ^ s_sw)]       = rg.a0;
        *(s16x8*)&AhS[s_row * 64 + ((s_k + 8) ^ s_sw)] = rg.a1;
        *(s16x8*)&AlS[s_row * 64 + (s_k ^ s_sw)]       = rg.a2;
        *(s16x8*)&AlS[s_row * 64 + ((s_k + 8) ^ s_sw)] = rg.a3;
        *(s16x8*)&BhS[tid * 8]         = rg.b0;
        *(s16x8*)&BhS[2048 + tid * 8]  = rg.b1;
        *(s16x8*)&BhS[4096 + tid * 8]  = rg.b2;
        *(s16x8*)&BhS[6144 + tid * 8]  = rg.b3;
        *(s16x8*)&BlS[tid * 8]         = rg.b4;
        *(s16x8*)&BlS[2048 + tid * 8]  = rg.b5;
        *(s16x8*)&BlS[4096 + tid * 8]  = rg.b6;
        *(s16x8*)&BlS[6144 + tid * 8]  = rg.b7;
    };

    issue(0);
    #pragma unroll 1
    for (int st = 0; st < 4; ++st) {
        __syncthreads();
        commit();
        if (st < 3) issue(st + 1);
        __syncthreads();
        #pragma unroll
        for (int kc = 0; kc < 4; ++kc) {
            int ak = (kc * 16 + afk) ^ fsw;
            s16x8 ah = *(const s16x8*)&AhS[arow * 64 + ak];
            s16x8 al = *(const s16x8*)&AlS[arow * 64 + ak];
            #pragma unroll
            for (int nt = 0; nt < 2; ++nt) {
                int brow = wc * 64 + nt * 32 + (l & 31);
                s16x8 bh = *(const s16x8*)&BhS[brow * 64 + ak];
                s16x8 bl = *(const s16x8*)&BlS[brow * 64 + ak];
                acc[nt] = __builtin_amdgcn_mfma_f32_32x32x16_bf16(ah, bh, acc[nt], 0, 0, 0);
                acc[nt] = __builtin_amdgcn_mfma_f32_32x32x16_bf16(ah, bl, acc[nt], 0, 0, 0);
                acc[nt] = __builtin_amdgcn_mfma_f32_32x32x16_bf16(al, bh, acc[nt], 0, 0, 0);
            }
        }
    }

    __syncthreads();
    float* fstage = (float*)lds;
    const int colb = l & 31;
    const int rq4  = (l >> 5) * 4;
    #pragma unroll
    for (int nt = 0; nt < 2; ++nt) {
        int col = wc * 64 + nt * 32 + colb;
        float bias_c = bias[col];
        #pragma unroll
        for (int g = 0; g < 4; ++g) {
            #pragma unroll
            for (int q = 0; q < 4; ++q) {
                int r = wr * 32 + q + g * 8 + rq4;
                fstage[r * 128 + col] = fmaxf(acc[nt][g * 4 + q] + bias_c, 0.f);
            }
        }
    }
    __syncthreads();
    int orow = tid >> 2;
    int ocol = (tid & 3) * 32;
    int grow = row0 + orow;
    if (grow < M) {
        #pragma unroll
        for (int c = 0; c < 32; c += 4) {
            float4 v = *(const float4*)&fstage[orow * 128 + ocol + c];
            *(float4*)(Yf + (size_t)grow * D + ocol + c) = v;
        }
    }
}

// ---------------- launch ----------------

extern "C" void kernel_launch(void* const* d_in, const int* in_sizes, int n_in,
                              void* d_out, int out_size, void* d_ws, size_t ws_size,
                              hipStream_t stream) {
    const float* h_station = (const float*)d_in[0];
    const float* h_feature = (const float*)d_in[1];
    const float* Wself     = (const float*)d_in[2];
    const float* Wneigh    = (const float*)d_in[3];
    const float* bias      = (const float*)d_in[4];
    const int* hf_src = (const int*)d_in[5];
    const int* hf_dst = (const int*)d_in[6];
    const int* tt_src = (const int*)d_in[7];
    const int* tt_dst = (const int*)d_in[8];

    const int NS = in_sizes[0] / D;
    const int NF = in_sizes[1] / D;
    const int E1 = in_sizes[5];
    const int E2 = in_sizes[7];
    const int NSP = (NS + 63) & ~63;    // padded rows: staging needs no bounds checks

    // workspace carve-up (with time-disjoint aliasing)
    char* ws = (char*)d_ws;
    size_t off = 0;
    auto alloc = [&](size_t bytes) -> void* {
        void* p = ws + off;
        off = (off + bytes + 255) & ~(size_t)255;
        return p;
    };
    unsigned short* st_h  = (unsigned short*)alloc((size_t)NSP * D * 2);
    unsigned short* st_l  = (unsigned short*)alloc((size_t)NSP * D * 2);
    unsigned short* n_h   = (unsigned short*)alloc((size_t)NSP * D * 2);
    unsigned short* n_l   = (unsigned short*)alloc((size_t)NSP * D * 2);
    unsigned short* hb_h  = (unsigned short*)alloc((size_t)NSP * D * 2 * 2);
    unsigned short* hb_l  = hb_h + (size_t)NSP * D;
    int* rp_hf    = (int*)alloc((size_t)(NS + 1) * sizeof(int));
    int* col_hf   = (int*)alloc((size_t)E1 * sizeof(int));
    int* rp_tt    = (int*)alloc((size_t)(NS + 1) * sizeof(int));
    int* col_tt   = (int*)alloc((size_t)E2 * sizeof(int));
    unsigned short* rank_hf = (unsigned short*)alloc((size_t)E1 * 2);
    unsigned short* rank_tt = (unsigned short*)alloc((size_t)E2 * 2);
    int  nb       = (NS + SCAN_EPB - 1) / SCAN_EPB;
    int* bs_hf    = (int*)alloc((size_t)nb * sizeof(int));
    int* bs_tt    = (int*)alloc((size_t)nb * sizeof(int));
    short* wt     = (short*)alloc((size_t)4 * 65536 * sizeof(short));

    // aliases (time-disjoint, stream-ordered):
    int* deg_hf = (int*)n_h;                 // NS*CPAD ints fit in n_h (dead until agg)
    int* deg_tt = (int*)n_l;
    unsigned short* feat_h = hb_h;           // NF*D shorts fit in hb (dead until GEMM1)

    const int tpb = 256;
    int ge   = (max(E1, E2) + tpb - 1) / tpb;
    int ge4  = ((max(E1, E2) + 3) / 4 + tpb - 1) / tpb;
    int gsp  = ((NS * D / 4) + tpb - 1) / tpb;
    int gft  = ((NF * D / 4) + tpb - 1) / tpb;
    int gzp  = ((NS * CPAD / 4) + tpb - 1) / tpb;

    prep_weights_kernel<<<64, tpb, 0, stream>>>(Wself, Wneigh, wt);
    tobf16_kernel<<<gft, tpb, 0, stream>>>(h_feature, feat_h, NF * D);
    split_rows_kernel<<<gsp, tpb, 0, stream>>>(h_station, st_h, st_l, NS * D);
    zero_pad_kernel<<<gzp, tpb, 0, stream>>>(deg_hf, deg_tt, NS * CPAD / 4);
    count_rank_kernel<<<ge, tpb, 0, stream>>>(hf_dst, tt_dst, deg_hf, deg_tt,
                                              rank_hf, rank_tt, E1, E2);
    scan_blocks_kernel<<<2 * nb, tpb, 0, stream>>>(deg_hf, rp_hf, bs_hf,
                                                   deg_tt, rp_tt, bs_tt, NS, nb);
    scan_offsets_kernel<<<2 * nb, tpb, 0, stream>>>(rp_hf, bs_hf, rp_tt, bs_tt,
                                                    NS, nb, E1, E2);
    fill_both_kernel<<<ge4, tpb, 0, stream>>>(hf_src, hf_dst, rank_hf, rp_hf, col_hf,
                                              tt_src, tt_dst, rank_tt, rp_tt, col_tt, E1, E2);

    int gagg  = (NS * 64 + tpb - 1) / tpb;
    int ggemm = NSP / 64;

    auto BI = [&](int lidx, int r) { return bias + (size_t)(lidx * 2 + r) * D; };
    auto WT = [&](int pair) { return wt + (size_t)pair * 65536; };

    float* out = (float*)d_out;

    // ---- layer 1 ----
    agg_mean_kernel<true><<<gagg, tpb, 0, stream>>>(feat_h, rp_hf, col_hf, n_h, n_l, NS);
    sage_mfma_kernel<false, false, true><<<ggemm, tpb, 0, stream>>>(
        st_h, st_l, n_h, n_l, WT(0), BI(0,0), nullptr, hb_h, hb_l, NS);
    agg_mean_kernel<true><<<gagg, tpb, 0, stream>>>(st_h, rp_tt, col_tt, n_h, n_l, NS);
    sage_mfma_kernel<true, false, true><<<ggemm, tpb, 0, stream>>>(
        st_h, st_l, n_h, n_l, WT(1), BI(0,1), nullptr, hb_h, hb_l, NS);

    // ---- layer 2 (in-place: blocks read only their own rows before writing) ----
    agg_mean_kernel<true><<<gagg, tpb, 0, stream>>>(hb_h, rp_tt, col_tt, n_h, n_l, NS);
    sage_mfma_kernel<false, false, true><<<ggemm, tpb, 0, stream>>>(
        hb_h, hb_l, n_h, n_l, WT(2), BI(1,1), nullptr, hb_h, hb_l, NS);

    // ---- layer 3 ----
    agg_mean_kernel<true><<<gagg, tpb, 0, stream>>>(hb_h, rp_tt, col_tt, n_h, n_l, NS);
    sage_mfma_kernel<false, true, false><<<ggemm, tpb, 0, stream>>>(
        hb_h, hb_l, n_h, n_l, WT(3), BI(2,1), out, nullptr, nullptr, NS);
}

// Round 11
// 299.350 us; speedup vs baseline: 1.1479x; 1.0887x over previous
//
#include <hip/hip_runtime.h>

#define D 128
#define CPAD 32

typedef __attribute__((ext_vector_type(8)))  short s16x8;
typedef __attribute__((ext_vector_type(4)))  short s16x4;
typedef __attribute__((ext_vector_type(16))) float f32x16;

static __device__ __forceinline__ unsigned short f2bf(float x) {
    unsigned u = __builtin_bit_cast(unsigned, x);
    unsigned r = (u + 0x7FFF + ((u >> 16) & 1)) >> 16;   // RNE
    return (unsigned short)r;
}
static __device__ __forceinline__ float bf2f(unsigned short h) {
    unsigned u = ((unsigned)h) << 16;
    return __builtin_bit_cast(float, u);
}

// ---------------- zero (must precede fat kernel's count part) ----------------

__global__ void zero_pad_kernel(int* __restrict__ a, int* __restrict__ b, int n4) {
    int i = blockIdx.x * blockDim.x + threadIdx.x;
    if (i < n4) {
        *(int4*)(a + i * 4) = make_int4(0, 0, 0, 0);
        *(int4*)(b + i * 4) = make_int4(0, 0, 0, 0);
    }
}

// ---------------- fat pre-kernel: {count_rank | split_rows | tobf16 | prep_weights} ----------------
// Round-10 lesson: count_rank is a ~24G atomics/s fabric wall (CPAD bought 8%,
// ILP nothing). Can't shrink it -> hide independent BW-bound work under it.
// Block ranges: [0,nbc)=count, [nbc,+nbs)=split_rows, [+,nbf)=tobf16, last 64=prep.

__global__ __launch_bounds__(256) void fat_pre_kernel(
    // count
    const int* __restrict__ hf_dst, const int* __restrict__ tt_dst,
    int* __restrict__ deg_hf, int* __restrict__ deg_tt,
    unsigned short* __restrict__ rank_hf, unsigned short* __restrict__ rank_tt,
    int E1, int E2, int nbc,
    // split_rows (h_station -> st_h/st_l)
    const float* __restrict__ h_station,
    unsigned short* __restrict__ st_h, unsigned short* __restrict__ st_l,
    int ns_elem, int nbs,
    // tobf16 (h_feature -> feat_h)
    const float* __restrict__ h_feature, unsigned short* __restrict__ feat_h,
    int nf_elem, int nbf,
    // prep weights
    const float* __restrict__ Wself, const float* __restrict__ Wneigh,
    short* __restrict__ wt)
{
    int b = blockIdx.x;
    int tid = threadIdx.x;
    if (b < nbc) {
        int i = b * 256 + tid;
        if (i < E1) {
            int r = atomicAdd(&deg_hf[hf_dst[i] * CPAD], 1);
            rank_hf[i] = (unsigned short)r;
        }
        if (i < E2) {
            int r = atomicAdd(&deg_tt[tt_dst[i] * CPAD], 1);
            rank_tt[i] = (unsigned short)r;
        }
        return;
    }
    b -= nbc;
    if (b < nbs) {
        int i = (b * 256 + tid) * 4;
        if (i < ns_elem) {
            float4 v = *(const float4*)(h_station + i);
            s16x4 hv, lv;
            unsigned short h0 = f2bf(v.x); hv[0] = (short)h0; lv[0] = (short)f2bf(v.x - bf2f(h0));
            unsigned short h1 = f2bf(v.y); hv[1] = (short)h1; lv[1] = (short)f2bf(v.y - bf2f(h1));
            unsigned short h2 = f2bf(v.z); hv[2] = (short)h2; lv[2] = (short)f2bf(v.z - bf2f(h2));
            unsigned short h3 = f2bf(v.w); hv[3] = (short)h3; lv[3] = (short)f2bf(v.w - bf2f(h3));
            *(s16x4*)(st_h + i) = hv;
            *(s16x4*)(st_l + i) = lv;
        }
        return;
    }
    b -= nbs;
    if (b < nbf) {
        int i = (b * 256 + tid) * 4;
        if (i < nf_elem) {
            float4 v = *(const float4*)(h_feature + i);
            s16x4 hv;
            hv[0] = (short)f2bf(v.x);
            hv[1] = (short)f2bf(v.y);
            hv[2] = (short)f2bf(v.z);
            hv[3] = (short)f2bf(v.w);
            *(s16x4*)(feat_h + i) = hv;
        }
        return;
    }
    b -= nbf;
    // prep weights: hi plane only (2-term split). 64 blocks.
    {
        int g = b * 256 + tid;               // [0, 16384)
        int m = g >> 11;
        int e = g & 2047;
        int n  = e >> 4;
        int kg = e & 15;
        int kk0 = kg >> 3;
        int kl0 = (kg & 7) * 8;
        int pair = m >> 1, s = m & 1;
        int l = (pair == 3) ? 2 : ((pair == 2) ? 1 : 0);
        int r = (pair == 0) ? 0 : 1;
        const float* W = (s ? Wneigh : Wself) + (size_t)(l * 2 + r) * D * D;
        s16x8 hv;
        #pragma unroll
        for (int c = 0; c < 8; ++c) {
            int k = kk0 * 64 + kl0 + c;
            hv[c] = (short)f2bf(W[(size_t)k * D + n]);
        }
        int ksb = kl0 ^ ((n & 7) << 3);
        size_t base = ((size_t)(pair * 2 + s) * 2 + kk0) * 8192;
        *(s16x8*)&wt[base + n * 64 + ksb] = hv;
    }
}

#define SCAN_EPB 1024

__global__ __launch_bounds__(256) void scan_blocks_kernel(
    const int* __restrict__ deg_hf, int* __restrict__ rp_hf, int* __restrict__ bs_hf,
    const int* __restrict__ deg_tt, int* __restrict__ rp_tt, int* __restrict__ bs_tt,
    int n, int nb)
{
    int gid = blockIdx.x;
    const int* deg; int* rp; int* bs; int b;
    if (gid < nb) { deg = deg_hf; rp = rp_hf; bs = bs_hf; b = gid; }
    else         { deg = deg_tt; rp = rp_tt; bs = bs_tt; b = gid - nb; }
    int t = threadIdx.x;
    int i0 = b * SCAN_EPB + t * 4;
    int4 v = make_int4(0, 0, 0, 0);
    if (i0 + 0 < n) v.x = deg[(size_t)(i0 + 0) * CPAD];
    if (i0 + 1 < n) v.y = deg[(size_t)(i0 + 1) * CPAD];
    if (i0 + 2 < n) v.z = deg[(size_t)(i0 + 2) * CPAD];
    if (i0 + 3 < n) v.w = deg[(size_t)(i0 + 3) * CPAD];
    __shared__ int sm[256];
    sm[t] = v.x + v.y + v.z + v.w;
    __syncthreads();
    for (int off = 1; off < 256; off <<= 1) {
        int x = (t >= off) ? sm[t - off] : 0;
        __syncthreads();
        sm[t] += x;
        __syncthreads();
    }
    int excl = (t > 0) ? sm[t - 1] : 0;
    if (i0 + 0 < n) rp[i0 + 0] = excl;
    if (i0 + 1 < n) rp[i0 + 1] = excl + v.x;
    if (i0 + 2 < n) rp[i0 + 2] = excl + v.x + v.y;
    if (i0 + 3 < n) rp[i0 + 3] = excl + v.x + v.y + v.z;
    if (t == 255) bs[b] = sm[255];
}

__global__ __launch_bounds__(256) void scan_offsets_kernel(
    int* __restrict__ rp_hf, const int* __restrict__ bs_hf,
    int* __restrict__ rp_tt, const int* __restrict__ bs_tt,
    int n, int nb, int E1, int E2)
{
    int gid = blockIdx.x;
    int* rp; const int* bs; int b; int E;
    if (gid < nb) { rp = rp_hf; bs = bs_hf; b = gid; E = E1; }
    else         { rp = rp_tt; bs = bs_tt; b = gid - nb; E = E2; }
    int t = threadIdx.x;
    int lane = t & 63;
    int partial = 0;
    for (int i = lane; i < b; i += 64) partial += bs[i];
    #pragma unroll
    for (int off = 32; off; off >>= 1) partial += __shfl_xor(partial, off);
    if (b == 0 && t == 0) rp[n] = E;
    if (partial == 0) return;
    int i0 = b * SCAN_EPB + t * 4;
    if (i0 + 0 < n) rp[i0 + 0] += partial;
    if (i0 + 1 < n) rp[i0 + 1] += partial;
    if (i0 + 2 < n) rp[i0 + 2] += partial;
    if (i0 + 3 < n) rp[i0 + 3] += partial;
}

__global__ void fill_both_kernel(
    const int* __restrict__ hf_src, const int* __restrict__ hf_dst,
    const unsigned short* __restrict__ rank_hf,
    const int* __restrict__ rp_hf, int* __restrict__ col_hf,
    const int* __restrict__ tt_src, const int* __restrict__ tt_dst,
    const unsigned short* __restrict__ rank_tt,
    const int* __restrict__ rp_tt, int* __restrict__ col_tt,
    int E1, int E2) {
    int i0 = (blockIdx.x * blockDim.x + threadIdx.x) * 4;
    if (i0 + 3 < E1) {
        int4 d = *(const int4*)(hf_dst + i0);
        int4 s = *(const int4*)(hf_src + i0);
        ushort4 r = *(const ushort4*)(rank_hf + i0);
        int p0 = rp_hf[d.x], p1 = rp_hf[d.y], p2 = rp_hf[d.z], p3 = rp_hf[d.w];
        col_hf[p0 + r.x] = s.x;
        col_hf[p1 + r.y] = s.y;
        col_hf[p2 + r.z] = s.z;
        col_hf[p3 + r.w] = s.w;
    } else {
        for (int j = 0; j < 4 && i0 + j < E1; ++j)
            col_hf[rp_hf[hf_dst[i0 + j]] + rank_hf[i0 + j]] = hf_src[i0 + j];
    }
    if (i0 + 3 < E2) {
        int4 d = *(const int4*)(tt_dst + i0);
        int4 s = *(const int4*)(tt_src + i0);
        ushort4 r = *(const ushort4*)(rank_tt + i0);
        int p0 = rp_tt[d.x], p1 = rp_tt[d.y], p2 = rp_tt[d.z], p3 = rp_tt[d.w];
        col_tt[p0 + r.x] = s.x;
        col_tt[p1 + r.y] = s.y;
        col_tt[p2 + r.z] = s.z;
        col_tt[p3 + r.w] = s.w;
    } else {
        for (int j = 0; j < 4 && i0 + j < E2; ++j)
            col_tt[rp_tt[tt_dst[i0 + j]] + rank_tt[i0 + j]] = tt_src[i0 + j];
    }
}

// ---------------- segment mean (one wave per dst row), bf16-hi gather, hi/lo out ----------------

__global__ __launch_bounds__(256) void agg_mean_kernel(
    const unsigned short* __restrict__ hsrc, const int* __restrict__ rowptr,
    const int* __restrict__ col,
    unsigned short* __restrict__ oh, unsigned short* __restrict__ ol, int ndst) {
    int w = (blockIdx.x * blockDim.x + threadIdx.x) >> 6;
    int lane = threadIdx.x & 63;
    if (w >= ndst) return;
    int beg = rowptr[w];
    int end = rowptr[w + 1];
    int deg = end - beg;
    float ax[8], ay[8];
    #pragma unroll
    for (int u = 0; u < 8; ++u) { ax[u] = 0.f; ay[u] = 0.f; }
    const unsigned short* baseb = hsrc + lane * 2;

    for (int b = beg; b < end; b += 64) {
        int n = min(64, end - b);
        int myidx = (lane < n) ? col[b + lane] : 0;
        int j = 0;
        for (; j + 8 <= n; j += 8) {
            int s[8];
            #pragma unroll
            for (int u = 0; u < 8; ++u) s[u] = __shfl(myidx, j + u);
            #pragma unroll
            for (int u = 0; u < 8; ++u) {
                unsigned v = *(const unsigned*)(baseb + (size_t)s[u] * D);
                ax[u] += __builtin_bit_cast(float, v << 16);
                ay[u] += __builtin_bit_cast(float, v & 0xFFFF0000u);
            }
        }
        for (; j < n; ++j) {
            int s0 = __shfl(myidx, j);
            unsigned v = *(const unsigned*)(baseb + (size_t)s0 * D);
            ax[0] += __builtin_bit_cast(float, v << 16);
            ay[0] += __builtin_bit_cast(float, v & 0xFFFF0000u);
        }
    }
    float inv = 1.0f / fmaxf((float)deg, 1.0f);
    float sx = (((ax[0] + ax[1]) + (ax[2] + ax[3])) + ((ax[4] + ax[5]) + (ax[6] + ax[7]))) * inv;
    float sy = (((ay[0] + ay[1]) + (ay[2] + ay[3])) + ((ay[4] + ay[5]) + (ay[6] + ay[7]))) * inv;
    unsigned short hx = f2bf(sx), hy = f2bf(sy);
    unsigned short lx = f2bf(sx - bf2f(hx)), ly = f2bf(sy - bf2f(hy));
    ((unsigned*)oh)[(size_t)w * 64 + lane] = (unsigned)hx | ((unsigned)hy << 16);
    ((unsigned*)ol)[(size_t)w * 64 + lane] = (unsigned)lx | ((unsigned)ly << 16);
}

// ---------------- fused SAGE layer, 2-term split-bf16 MFMA, BM=64 ----------------
// Round-11: A exact (hi+lo), W rounded to bf16 (hi only). Dropped A@Wl term
// ~1.5e-3/layer. LDS 32KB -> 5 blocks/CU (was 3 at 48KB): attacks the
// latency-starvation that reg-prefetch alone couldn't fix.

struct StageRegs {
    s16x8 a0, a1, a2, a3;        // Ah x2, Al x2
    s16x8 b0, b1, b2, b3;        // Bh x4
};

template<bool ACC, bool WF32, bool WBF>
__global__ __launch_bounds__(256) void sage_mfma_kernel(
    const unsigned short* __restrict__ Ah_g, const unsigned short* __restrict__ Al_g,
    const unsigned short* __restrict__ Nh_g, const unsigned short* __restrict__ Nl_g,
    const short* __restrict__ wtp, const float* __restrict__ bias,
    float* __restrict__ Yf, unsigned short* __restrict__ Yh, unsigned short* __restrict__ Yl,
    int M)
{
    __shared__ short lds[16384];   // 32KB: Ah[0:4k] Al[4k:8k] Bh[8k:16k] (shorts)
    short* AhS = lds;
    short* AlS = lds + 4096;
    short* BhS = lds + 8192;

    const int tid = threadIdx.x;
    const int l = tid & 63, w = tid >> 6;
    const int wr = w >> 1, wc = w & 1;
    const int row0 = blockIdx.x * 64;

    f32x16 acc[2] = {};

    const int s_row = tid >> 2;           // 0..63
    const int s_k   = (tid & 3) * 16;     // 0,16,32,48
    const int s_sw  = (s_row & 7) << 3;
    const int arow  = wr * 32 + (l & 31);
    const int fsw   = (l & 7) << 3;
    const int afk   = (l >> 5) * 8;

    StageRegs rg;

    auto issue = [&](int st) {
        int s = st >> 1, kk0 = st & 1;
        const unsigned short* Hg = s ? Nh_g : Ah_g;
        const unsigned short* Lg = s ? Nl_g : Al_g;
        const unsigned short* hrow = Hg + (size_t)(row0 + s_row) * D + kk0 * 64 + s_k;
        const unsigned short* lrow = Lg + (size_t)(row0 + s_row) * D + kk0 * 64 + s_k;
        rg.a0 = *(const s16x8*)(hrow);
        rg.a1 = *(const s16x8*)(hrow + 8);
        rg.a2 = *(const s16x8*)(lrow);
        rg.a3 = *(const s16x8*)(lrow + 8);
        const short* wsrc = wtp + (size_t)st * 8192;
        rg.b0 = *(const s16x8*)(wsrc + tid * 8);
        rg.b1 = *(const s16x8*)(wsrc + 2048 + tid * 8);
        rg.b2 = *(const s16x8*)(wsrc + 4096 + tid * 8);
        rg.b3 = *(const s16x8*)(wsrc + 6144 + tid * 8);
    };
    auto commit = [&]() {
        *(s16x8*)&AhS[s_row * 64 + (s_k ^ s_sw)]       = rg.a0;
        *(s16x8*)&AhS[s_row * 64 + ((s_k + 8) ^ s_sw)] = rg.a1;
        *(s16x8*)&AlS[s_row * 64 + (s_k ^ s_sw)]       = rg.a2;
        *(s16x8*)&AlS[s_row * 64 + ((s_k + 8) ^ s_sw)] = rg.a3;
        *(s16x8*)&BhS[tid * 8]         = rg.b0;
        *(s16x8*)&BhS[2048 + tid * 8]  = rg.b1;
        *(s16x8*)&BhS[4096 + tid * 8]  = rg.b2;
        *(s16x8*)&BhS[6144 + tid * 8]  = rg.b3;
    };

    issue(0);
    #pragma unroll 1
    for (int st = 0; st < 4; ++st) {
        __syncthreads();              // prior-stage LDS reads done
        commit();
        if (st < 3) issue(st + 1);    // loads drain during MFMA below (T14)
        __syncthreads();
        #pragma unroll
        for (int kc = 0; kc < 4; ++kc) {
            int ak = (kc * 16 + afk) ^ fsw;
            s16x8 ah = *(const s16x8*)&AhS[arow * 64 + ak];
            s16x8 al = *(const s16x8*)&AlS[arow * 64 + ak];
            #pragma unroll
            for (int nt = 0; nt < 2; ++nt) {
                int brow = wc * 64 + nt * 32 + (l & 31);
                s16x8 bh = *(const s16x8*)&BhS[brow * 64 + ak];
                acc[nt] = __builtin_amdgcn_mfma_f32_32x32x16_bf16(ah, bh, acc[nt], 0, 0, 0);
                acc[nt] = __builtin_amdgcn_mfma_f32_32x32x16_bf16(al, bh, acc[nt], 0, 0, 0);
            }
        }
    }

    // ---- epilogue: acc -> fp32 LDS stage (32KB) -> coalesced global IO ----
    __syncthreads();
    float* fstage = (float*)lds;    // 64 x 128 fp32 = 32KB
    const int colb = l & 31;
    const int rq4  = (l >> 5) * 4;
    #pragma unroll
    for (int nt = 0; nt < 2; ++nt) {
        int col = wc * 64 + nt * 32 + colb;
        float bias_c = bias[col];
        #pragma unroll
        for (int g = 0; g < 4; ++g) {
            #pragma unroll
            for (int q = 0; q < 4; ++q) {
                int r = wr * 32 + q + g * 8 + rq4;
                fstage[r * 128 + col] = fmaxf(acc[nt][g * 4 + q] + bias_c, 0.f);
            }
        }
    }
    __syncthreads();
    int orow = tid >> 2;
    int ocol = (tid & 3) * 32;
    int grow = row0 + orow;
    if (grow < M) {
        float vals[32];
        #pragma unroll
        for (int c = 0; c < 32; c += 4)
            *(float4*)&vals[c] = *(const float4*)&fstage[orow * 128 + ocol + c];
        size_t base = (size_t)grow * D + ocol;
        if (ACC) {
            #pragma unroll
            for (int c8 = 0; c8 < 4; ++c8) {
                s16x8 oh = *(const s16x8*)(Yh + base + c8 * 8);
                s16x8 ol = *(const s16x8*)(Yl + base + c8 * 8);
                #pragma unroll
                for (int e = 0; e < 8; ++e)
                    vals[c8 * 8 + e] += bf2f((unsigned short)oh[e]) + bf2f((unsigned short)ol[e]);
            }
        }
        if (WF32) {
            #pragma unroll
            for (int c = 0; c < 32; c += 4)
                *(float4*)(Yf + base + c) = *(const float4*)&vals[c];
        }
        if (WBF) {
            #pragma unroll
            for (int c8 = 0; c8 < 4; ++c8) {
                s16x8 hv, lv;
                #pragma unroll
                for (int e = 0; e < 8; ++e) {
                    float v = vals[c8 * 8 + e];
                    unsigned short h = f2bf(v);
                    hv[e] = (short)h;
                    lv[e] = (short)f2bf(v - bf2f(h));
                }
                *(s16x8*)(Yh + base + c8 * 8) = hv;
                *(s16x8*)(Yl + base + c8 * 8) = lv;
            }
        }
    }
}

// ---------------- launch ----------------

extern "C" void kernel_launch(void* const* d_in, const int* in_sizes, int n_in,
                              void* d_out, int out_size, void* d_ws, size_t ws_size,
                              hipStream_t stream) {
    const float* h_station = (const float*)d_in[0];
    const float* h_feature = (const float*)d_in[1];
    const float* Wself     = (const float*)d_in[2];
    const float* Wneigh    = (const float*)d_in[3];
    const float* bias      = (const float*)d_in[4];
    const int* hf_src = (const int*)d_in[5];
    const int* hf_dst = (const int*)d_in[6];
    const int* tt_src = (const int*)d_in[7];
    const int* tt_dst = (const int*)d_in[8];

    const int NS = in_sizes[0] / D;
    const int NF = in_sizes[1] / D;
    const int E1 = in_sizes[5];
    const int E2 = in_sizes[7];
    const int NSP = (NS + 63) & ~63;

    // workspace carve-up (with time-disjoint aliasing)
    char* ws = (char*)d_ws;
    size_t off = 0;
    auto alloc = [&](size_t bytes) -> void* {
        void* p = ws + off;
        off = (off + bytes + 255) & ~(size_t)255;
        return p;
    };
    unsigned short* st_h  = (unsigned short*)alloc((size_t)NSP * D * 2);
    unsigned short* st_l  = (unsigned short*)alloc((size_t)NSP * D * 2);
    unsigned short* n_h   = (unsigned short*)alloc((size_t)NSP * D * 2);
    unsigned short* n_l   = (unsigned short*)alloc((size_t)NSP * D * 2);
    unsigned short* hb_h  = (unsigned short*)alloc((size_t)NSP * D * 2 * 2);
    unsigned short* hb_l  = hb_h + (size_t)NSP * D;
    int* rp_hf    = (int*)alloc((size_t)(NS + 1) * sizeof(int));
    int* col_hf   = (int*)alloc((size_t)E1 * sizeof(int));
    int* rp_tt    = (int*)alloc((size_t)(NS + 1) * sizeof(int));
    int* col_tt   = (int*)alloc((size_t)E2 * sizeof(int));
    unsigned short* rank_hf = (unsigned short*)alloc((size_t)E1 * 2);
    unsigned short* rank_tt = (unsigned short*)alloc((size_t)E2 * 2);
    int  nb       = (NS + SCAN_EPB - 1) / SCAN_EPB;
    int* bs_hf    = (int*)alloc((size_t)nb * sizeof(int));
    int* bs_tt    = (int*)alloc((size_t)nb * sizeof(int));
    short* wt     = (short*)alloc((size_t)4 * 32768 * sizeof(short));   // hi plane only

    // aliases (time-disjoint, stream-ordered):
    int* deg_hf = (int*)n_h;                 // NS*CPAD ints in n_h (dead until agg1)
    int* deg_tt = (int*)n_l;
    unsigned short* feat_h = hb_h;           // NF*D shorts in hb (dead until GEMM1)

    const int tpb = 256;
    int ge4  = ((max(E1, E2) + 3) / 4 + tpb - 1) / tpb;
    int gzp  = ((NS * CPAD / 4) + tpb - 1) / tpb;

    int nbc = (max(E1, E2) + tpb - 1) / tpb;
    int nbs = (NS * D / 4 + tpb - 1) / tpb;
    int nbf = (NF * D / 4 + tpb - 1) / tpb;

    zero_pad_kernel<<<gzp, tpb, 0, stream>>>(deg_hf, deg_tt, NS * CPAD / 4);
    fat_pre_kernel<<<nbc + nbs + nbf + 64, tpb, 0, stream>>>(
        hf_dst, tt_dst, deg_hf, deg_tt, rank_hf, rank_tt, E1, E2, nbc,
        h_station, st_h, st_l, NS * D, nbs,
        h_feature, feat_h, NF * D, nbf,
        Wself, Wneigh, wt);
    scan_blocks_kernel<<<2 * nb, tpb, 0, stream>>>(deg_hf, rp_hf, bs_hf,
                                                   deg_tt, rp_tt, bs_tt, NS, nb);
    scan_offsets_kernel<<<2 * nb, tpb, 0, stream>>>(rp_hf, bs_hf, rp_tt, bs_tt,
                                                    NS, nb, E1, E2);
    fill_both_kernel<<<ge4, tpb, 0, stream>>>(hf_src, hf_dst, rank_hf, rp_hf, col_hf,
                                              tt_src, tt_dst, rank_tt, rp_tt, col_tt, E1, E2);

    int gagg  = (NS * 64 + tpb - 1) / tpb;
    int ggemm = NSP / 64;

    auto BI = [&](int lidx, int r) { return bias + (size_t)(lidx * 2 + r) * D; };
    auto WT = [&](int pair) { return wt + (size_t)pair * 32768; };

    float* out = (float*)d_out;

    // ---- layer 1 ----
    agg_mean_kernel<<<gagg, tpb, 0, stream>>>(feat_h, rp_hf, col_hf, n_h, n_l, NS);
    sage_mfma_kernel<false, false, true><<<ggemm, tpb, 0, stream>>>(
        st_h, st_l, n_h, n_l, WT(0), BI(0,0), nullptr, hb_h, hb_l, NS);
    agg_mean_kernel<<<gagg, tpb, 0, stream>>>(st_h, rp_tt, col_tt, n_h, n_l, NS);
    sage_mfma_kernel<true, false, true><<<ggemm, tpb, 0, stream>>>(
        st_h, st_l, n_h, n_l, WT(1), BI(0,1), nullptr, hb_h, hb_l, NS);

    // ---- layer 2 (in-place: blocks read only their own rows before writing) ----
    agg_mean_kernel<<<gagg, tpb, 0, stream>>>(hb_h, rp_tt, col_tt, n_h, n_l, NS);
    sage_mfma_kernel<false, false, true><<<ggemm, tpb, 0, stream>>>(
        hb_h, hb_l, n_h, n_l, WT(2), BI(1,1), nullptr, hb_h, hb_l, NS);

    // ---- layer 3 ----
    agg_mean_kernel<<<gagg, tpb, 0, stream>>>(hb_h, rp_tt, col_tt, n_h, n_l, NS);
    sage_mfma_kernel<false, true, false><<<ggemm, tpb, 0, stream>>>(
        hb_h, hb_l, n_h, n_l, WT(3), BI(2,1), out, nullptr, nullptr, NS);
}